// Round 2
// baseline (482.470 us; speedup 1.0000x reference)
//
#include <hip/hip_runtime.h>
#include <hip/hip_bf16.h>

#define EPS 1e-5f
#define NE_ 100000
#define B_  256

// =====================================================================
// Kernel 1: per-sample feature pipeline -> hT[100][256] (fp32, transposed)
//   gather e1 -> BN0 ; gather rel -> BN_rel -> filters
//   dynamic conv 5x5 VALID on 10x10 -> (100,6,6) -> BN1+ReLU
//   fc 3600->100 + BN2 + ReLU
// grid = 256 blocks (one per sample), block = 256 threads
// =====================================================================
__global__ __launch_bounds__(256) void k_features(
    const float* __restrict__ emb_e,
    const float* __restrict__ emb_rel,
    const float* __restrict__ bnr_g, const float* __restrict__ bnr_b,
    const float* __restrict__ bnr_m, const float* __restrict__ bnr_v,
    const float* __restrict__ bn0_g, const float* __restrict__ bn0_b,
    const float* __restrict__ bn0_m, const float* __restrict__ bn0_v,
    const float* __restrict__ bn1_g, const float* __restrict__ bn1_b,
    const float* __restrict__ bn1_m, const float* __restrict__ bn1_v,
    const float* __restrict__ fc_w,  const float* __restrict__ fc_b,
    const float* __restrict__ bn2_g, const float* __restrict__ bn2_b,
    const float* __restrict__ bn2_m, const float* __restrict__ bn2_v,
    const int* __restrict__ e1, const int* __restrict__ rel,
    float* __restrict__ hT)    // [100][256]
{
    __shared__ float x0s[100];    // BN0'd entity image (10x10)
    __shared__ float fs[2500];    // BN_rel'd filters (100 ch x 25)
    __shared__ float x1s[3600];   // conv+BN1+ReLU output, layout i = c*36 + p

    const int b = blockIdx.x;
    const int t = threadIdx.x;
    const int ei = e1[b];
    const int ri = rel[b];

    // ---- x0 = BN0(emb_e[e1]) ----
    if (t < 100) {
        float sc = bn0_g[0] * rsqrtf(bn0_v[0] + EPS);
        float sh = bn0_b[0] - bn0_m[0] * sc;
        x0s[t] = emb_e[ei * 100 + t] * sc + sh;
    }
    // ---- filters = BN_rel(emb_rel[rel]) ----
    for (int j = t; j < 2500; j += 256) {
        float sc = bnr_g[j] * rsqrtf(bnr_v[j] + EPS);
        fs[j] = (emb_rel[(size_t)ri * 2500 + j] - bnr_m[j]) * sc + bnr_b[j];
    }
    __syncthreads();

    // ---- conv: out[c][p] = sum_k fs[c*25+k] * x0[patch(p,k)] ; BN1+ReLU ----
    // iterate idx = p*100 + c so lanes share p (x0 reads broadcast),
    // consecutive c (fs reads stride-25 -> conflict-free)
    for (int idx = t; idx < 3600; idx += 256) {
        int p = idx / 100;
        int c = idx - p * 100;
        int hh = p / 6, ww = p - hh * 6;
        float sum = 0.f;
        #pragma unroll
        for (int ky = 0; ky < 5; ky++) {
            #pragma unroll
            for (int kx = 0; kx < 5; kx++) {
                sum += x0s[(hh + ky) * 10 + ww + kx] * fs[c * 25 + ky * 5 + kx];
            }
        }
        float sc = bn1_g[c] * rsqrtf(bn1_v[c] + EPS);
        float y = (sum - bn1_m[c]) * sc + bn1_b[c];
        x1s[c * 36 + p] = fmaxf(y, 0.f);
    }
    __syncthreads();

    // ---- fc: h[o] = BN2(relu? no: relu(BN2(x@W+b))) ----
    if (t < 100) {
        float sum = fc_b[t];
        #pragma unroll 8
        for (int i = 0; i < 3600; i++) {
            sum += x1s[i] * fc_w[(size_t)i * 100 + t];
        }
        float sc = bn2_g[t] * rsqrtf(bn2_v[t] + EPS);
        float y = (sum - bn2_m[t]) * sc + bn2_b[t];
        hT[t * 256 + b] = fmaxf(y, 0.f);   // transposed store for kernel 2 staging
    }
}

// =====================================================================
// Kernel 2: out[b][e] = sigmoid( h[b] . emb_e[e] + bias[e] ), fp32 out
// fp32 tiled GEMM: 64 b-rows x 64 entities per block, K=100
// grid = (ceil(NE/64), 4), block = 256 (tx=0..15 entity-quads, ty=0..15 b-quads)
// =====================================================================
__global__ __launch_bounds__(256) void k_scores(
    const float* __restrict__ emb_e,
    const float* __restrict__ bias,
    const float* __restrict__ hT,          // [100][256]
    float* __restrict__ out)               // [256][NE] fp32
{
    // k-major h tile, +4 pad keeps float4 reads 16B-aligned, conflict-free
    __shared__ __align__(16) float hs[100][68];
    // row-major emb tile, +1 pad -> compute reads land on distinct banks (2-way = free)
    __shared__ __align__(16) float es[64][101];

    const int t = threadIdx.x;
    const int e0 = blockIdx.x * 64;
    const int b0 = blockIdx.y * 64;

    // ---- stage hT (fp32) -> hs[k][bl] ----
    for (int idx = t; idx < 1600; idx += 256) {
        int k = idx >> 4;
        int b4 = idx & 15;
        const float4 v = *(const float4*)(hT + k * 256 + b0 + b4 * 4);
        hs[k][b4 * 4 + 0] = v.x;
        hs[k][b4 * 4 + 1] = v.y;
        hs[k][b4 * 4 + 2] = v.z;
        hs[k][b4 * 4 + 3] = v.w;
    }
    // ---- stage emb_e -> es[el][k], coalesced 16B global loads ----
    for (int idx = t; idx < 1600; idx += 256) {
        int el = idx / 25;
        int k4 = idx - el * 25;
        int e = e0 + el;
        float4 v = make_float4(0.f, 0.f, 0.f, 0.f);
        if (e < NE_) {
            v = *(const float4*)(emb_e + (size_t)e * 100 + k4 * 4);
        }
        es[el][k4 * 4 + 0] = v.x;
        es[el][k4 * 4 + 1] = v.y;
        es[el][k4 * 4 + 2] = v.z;
        es[el][k4 * 4 + 3] = v.w;
    }
    __syncthreads();

    const int tx = t & 15;   // entity quad
    const int ty = t >> 4;   // batch quad
    float acc[4][4] = {{0.f}};

    #pragma unroll 4
    for (int k = 0; k < 100; k++) {
        const float4 a = *(const float4*)&hs[k][ty * 4];  // broadcast across tx
        const float bv0 = es[tx * 4 + 0][k];
        const float bv1 = es[tx * 4 + 1][k];
        const float bv2 = es[tx * 4 + 2][k];
        const float bv3 = es[tx * 4 + 3][k];
        acc[0][0] += a.x * bv0; acc[0][1] += a.x * bv1; acc[0][2] += a.x * bv2; acc[0][3] += a.x * bv3;
        acc[1][0] += a.y * bv0; acc[1][1] += a.y * bv1; acc[1][2] += a.y * bv2; acc[1][3] += a.y * bv3;
        acc[2][0] += a.z * bv0; acc[2][1] += a.z * bv1; acc[2][2] += a.z * bv2; acc[2][3] += a.z * bv3;
        acc[3][0] += a.w * bv0; acc[3][1] += a.w * bv1; acc[3][2] += a.w * bv2; acc[3][3] += a.w * bv3;
    }

    // ---- epilogue: + bias, sigmoid, fp32 float4 store ----
    const int ecol = e0 + tx * 4;
    if (ecol < NE_) {
        const float4 bb = *(const float4*)(bias + ecol);
        #pragma unroll
        for (int i = 0; i < 4; i++) {
            const int brow = b0 + ty * 4 + i;
            float4 o;
            o.x = 1.f / (1.f + __expf(-(acc[i][0] + bb.x)));
            o.y = 1.f / (1.f + __expf(-(acc[i][1] + bb.y)));
            o.z = 1.f / (1.f + __expf(-(acc[i][2] + bb.z)));
            o.w = 1.f / (1.f + __expf(-(acc[i][3] + bb.w)));
            *(float4*)(out + (size_t)brow * NE_ + ecol) = o;
        }
    }
}

extern "C" void kernel_launch(void* const* d_in, const int* in_sizes, int n_in,
                              void* d_out, int out_size, void* d_ws, size_t ws_size,
                              hipStream_t stream) {
    const float* emb_e   = (const float*)d_in[0];
    const float* emb_rel = (const float*)d_in[1];
    const float* bnr_g   = (const float*)d_in[2];
    const float* bnr_b   = (const float*)d_in[3];
    const float* bnr_m   = (const float*)d_in[4];
    const float* bnr_v   = (const float*)d_in[5];
    const float* bn0_g   = (const float*)d_in[6];
    const float* bn0_b   = (const float*)d_in[7];
    const float* bn0_m   = (const float*)d_in[8];
    const float* bn0_v   = (const float*)d_in[9];
    const float* bn1_g   = (const float*)d_in[10];
    const float* bn1_b   = (const float*)d_in[11];
    const float* bn1_m   = (const float*)d_in[12];
    const float* bn1_v   = (const float*)d_in[13];
    const float* fc_w    = (const float*)d_in[14];
    const float* fc_b    = (const float*)d_in[15];
    const float* bn2_g   = (const float*)d_in[16];
    const float* bn2_b   = (const float*)d_in[17];
    const float* bn2_m   = (const float*)d_in[18];
    const float* bn2_v   = (const float*)d_in[19];
    const float* bias    = (const float*)d_in[20];
    const int* e1  = (const int*)d_in[21];
    const int* rel = (const int*)d_in[22];

    float* hT = (float*)d_ws;   // 100 x 256 fp32 = 102.4 KB

    k_features<<<dim3(B_), dim3(256), 0, stream>>>(
        emb_e, emb_rel,
        bnr_g, bnr_b, bnr_m, bnr_v,
        bn0_g, bn0_b, bn0_m, bn0_v,
        bn1_g, bn1_b, bn1_m, bn1_v,
        fc_w, fc_b,
        bn2_g, bn2_b, bn2_m, bn2_v,
        e1, rel, hT);

    k_scores<<<dim3((NE_ + 63) / 64, 4), dim3(256), 0, stream>>>(
        emb_e, bias, hT, (float*)d_out);
}

// Round 3
// 374.182 us; speedup vs baseline: 1.2894x; 1.2894x over previous
//
#include <hip/hip_runtime.h>
#include <hip/hip_bf16.h>

#define EPS 1e-5f
#define NE_ 100000
#define B_  256

// ws layout (fp32):
//   x1       : [256][3600]          offset 0        (3,686,400 B)
//   partials : [16][256][100]       offset 921600 f  (1,638,400 B)
//   hT       : [100][256]           offset 1331200 f (  102,400 B)
#define WS_X1    0
#define WS_PART  921600
#define WS_HT    1331200

// =====================================================================
// Kernel 1: conv features. One block per sample.
//   x1[b][c*36 + p] = relu(BN1(conv(BN0(emb_e[e1[b]]), BN_rel(emb_rel[rel[b]]))))
// =====================================================================
__global__ __launch_bounds__(256) void k_conv(
    const float* __restrict__ emb_e,
    const float* __restrict__ emb_rel,
    const float* __restrict__ bnr_g, const float* __restrict__ bnr_b,
    const float* __restrict__ bnr_m, const float* __restrict__ bnr_v,
    const float* __restrict__ bn0_g, const float* __restrict__ bn0_b,
    const float* __restrict__ bn0_m, const float* __restrict__ bn0_v,
    const float* __restrict__ bn1_g, const float* __restrict__ bn1_b,
    const float* __restrict__ bn1_m, const float* __restrict__ bn1_v,
    const int* __restrict__ e1, const int* __restrict__ rel,
    float* __restrict__ x1)     // [256][3600]
{
    __shared__ float x0s[100];
    __shared__ float fs[2500];

    const int b = blockIdx.x;
    const int t = threadIdx.x;
    const int ei = e1[b];
    const int ri = rel[b];

    if (t < 100) {
        float sc = bn0_g[0] * rsqrtf(bn0_v[0] + EPS);
        float sh = bn0_b[0] - bn0_m[0] * sc;
        x0s[t] = emb_e[(size_t)ei * 100 + t] * sc + sh;
    }
    for (int j = t; j < 2500; j += 256) {
        float sc = bnr_g[j] * rsqrtf(bnr_v[j] + EPS);
        fs[j] = (emb_rel[(size_t)ri * 2500 + j] - bnr_m[j]) * sc + bnr_b[j];
    }
    __syncthreads();

    // idx = c*36 + p : consecutive lanes share c (fs broadcast) and have
    // consecutive p (x0 reads near-contiguous, x1 stores coalesced)
    for (int idx = t; idx < 3600; idx += 256) {
        int c = idx / 36;
        int p = idx - c * 36;
        int hh = p / 6, ww = p - hh * 6;
        float sum = 0.f;
        #pragma unroll
        for (int ky = 0; ky < 5; ky++) {
            #pragma unroll
            for (int kx = 0; kx < 5; kx++) {
                sum += x0s[(hh + ky) * 10 + ww + kx] * fs[c * 25 + ky * 5 + kx];
            }
        }
        float sc = bn1_g[c] * rsqrtf(bn1_v[c] + EPS);
        float y = (sum - bn1_m[c]) * sc + bn1_b[c];
        x1[(size_t)b * 3600 + idx] = fmaxf(y, 0.f);
    }
}

// =====================================================================
// Kernel 2: fc GEMM, split-K.
//   partials[ks][b][o] = sum_{k in chunk ks} x1[b][k] * W[k][o]
// grid (16 m-tiles, 16 k-splits), block 256.
// thread: o = t&127 (entity-out col, <100 valid), mg = t>>7; 8 rows each.
// =====================================================================
__global__ __launch_bounds__(256) void k_fc(
    const float* __restrict__ x1,     // [256][3600]
    const float* __restrict__ fc_w,   // [3600][100]
    float* __restrict__ partials)     // [16][256][100]
{
    __shared__ float x1s[16][226];
    const int b0  = blockIdx.x * 16;
    const int ks  = blockIdx.y;
    const int kc0 = ks * 225;
    const int t = threadIdx.x;

    for (int idx = t; idx < 16 * 225; idx += 256) {
        int m = idx / 225, kk = idx - m * 225;
        x1s[m][kk] = x1[(size_t)(b0 + m) * 3600 + kc0 + kk];
    }
    __syncthreads();

    const int o  = t & 127;
    const int mg = t >> 7;
    if (o >= 100) return;

    float acc[8] = {0.f, 0.f, 0.f, 0.f, 0.f, 0.f, 0.f, 0.f};
    const float* wp = fc_w + (size_t)kc0 * 100 + o;

    for (int k0 = 0; k0 < 225; k0 += 9) {   // 25 batches of 9
        float wv[9];
        #pragma unroll
        for (int u = 0; u < 9; u++) wv[u] = wp[(size_t)(k0 + u) * 100];
        #pragma unroll
        for (int u = 0; u < 9; u++) {
            #pragma unroll
            for (int j = 0; j < 8; j++)
                acc[j] += x1s[mg + 2 * j][k0 + u] * wv[u];
        }
    }
    #pragma unroll
    for (int j = 0; j < 8; j++)
        partials[(size_t)ks * 25600 + (size_t)(b0 + mg + 2 * j) * 100 + o] = acc[j];
}

// =====================================================================
// Kernel 3: reduce split-K + fc_b + BN2 + ReLU -> hT[100][256]
// grid 100 blocks x 256 (25600 = 256*100 exactly)
// =====================================================================
__global__ __launch_bounds__(256) void k_reduce(
    const float* __restrict__ partials,   // [16][256][100]
    const float* __restrict__ fc_b,
    const float* __restrict__ bn2_g, const float* __restrict__ bn2_b,
    const float* __restrict__ bn2_m, const float* __restrict__ bn2_v,
    float* __restrict__ hT)               // [100][256]
{
    const int flat = blockIdx.x * 256 + threadIdx.x;   // b*100 + o
    const int b = flat / 100;
    const int o = flat - b * 100;
    float s = fc_b[o];
    #pragma unroll
    for (int ks = 0; ks < 16; ks++) s += partials[(size_t)ks * 25600 + flat];
    float sc = bn2_g[o] * rsqrtf(bn2_v[o] + EPS);
    float y = (s - bn2_m[o]) * sc + bn2_b[o];
    hT[o * 256 + b] = fmaxf(y, 0.f);
}

// =====================================================================
// Kernel 4: out[b][e] = sigmoid(h[b].emb_e[e] + bias[e])
// tile 32 b-rows x 128 entities; block 256; grid (782, 8)
// thread: tx = t&127 -> entity; th = t>>7 -> 16-row half; acc[16]
// LDS only 14.4 KB -> high residency; emb read as per-thread float4.
// =====================================================================
__global__ __launch_bounds__(256) void k_scores(
    const float* __restrict__ emb_e,
    const float* __restrict__ bias,
    const float* __restrict__ hT,      // [100][256]
    float* __restrict__ out)           // [256][NE]
{
    __shared__ float hs[100][36];      // +4 pad: staging stores ~2-way max
    const int t  = threadIdx.x;
    const int e0 = blockIdx.x * 128;
    const int b0 = blockIdx.y * 32;

    // stage h tile: 3200 floats as 800 float4 loads (aligned: 256,32 mult of 4)
    for (int idx = t; idx < 800; idx += 256) {
        int k = idx >> 3, b4 = idx & 7;
        float4 v = *(const float4*)(hT + k * 256 + b0 + b4 * 4);
        *(float4*)&hs[k][b4 * 4] = v;
    }
    __syncthreads();

    const int tx = t & 127;
    const int th = t >> 7;             // 0/1 -> rows th*16 .. th*16+15
    const int e  = e0 + tx;
    const int el = (e < NE_) ? e : (NE_ - 1);
    const float4* erow = (const float4*)(emb_e + (size_t)el * 100); // 400B-aligned

    float acc[16];
    #pragma unroll
    for (int j = 0; j < 16; j++) acc[j] = 0.f;

    #pragma unroll 2
    for (int k4 = 0; k4 < 25; k4++) {
        const float4 w = erow[k4];
        const float wv[4] = {w.x, w.y, w.z, w.w};
        #pragma unroll
        for (int kk = 0; kk < 4; kk++) {
            const float* hp = &hs[k4 * 4 + kk][th * 16];  // wave-broadcast reads
            const float wk = wv[kk];
            #pragma unroll
            for (int j = 0; j < 16; j++)
                acc[j] += hp[j] * wk;
        }
    }

    if (e < NE_) {
        const float bb = bias[e];
        #pragma unroll
        for (int j = 0; j < 16; j++) {
            const int brow = b0 + th * 16 + j;
            out[(size_t)brow * NE_ + e] = 1.f / (1.f + __expf(-(acc[j] + bb)));
        }
    }
}

extern "C" void kernel_launch(void* const* d_in, const int* in_sizes, int n_in,
                              void* d_out, int out_size, void* d_ws, size_t ws_size,
                              hipStream_t stream) {
    const float* emb_e   = (const float*)d_in[0];
    const float* emb_rel = (const float*)d_in[1];
    const float* bnr_g   = (const float*)d_in[2];
    const float* bnr_b   = (const float*)d_in[3];
    const float* bnr_m   = (const float*)d_in[4];
    const float* bnr_v   = (const float*)d_in[5];
    const float* bn0_g   = (const float*)d_in[6];
    const float* bn0_b   = (const float*)d_in[7];
    const float* bn0_m   = (const float*)d_in[8];
    const float* bn0_v   = (const float*)d_in[9];
    const float* bn1_g   = (const float*)d_in[10];
    const float* bn1_b   = (const float*)d_in[11];
    const float* bn1_m   = (const float*)d_in[12];
    const float* bn1_v   = (const float*)d_in[13];
    const float* fc_w    = (const float*)d_in[14];
    const float* fc_b    = (const float*)d_in[15];
    const float* bn2_g   = (const float*)d_in[16];
    const float* bn2_b   = (const float*)d_in[17];
    const float* bn2_m   = (const float*)d_in[18];
    const float* bn2_v   = (const float*)d_in[19];
    const float* bias    = (const float*)d_in[20];
    const int* e1  = (const int*)d_in[21];
    const int* rel = (const int*)d_in[22];

    float* ws       = (float*)d_ws;
    float* x1       = ws + WS_X1;
    float* partials = ws + WS_PART;
    float* hT       = ws + WS_HT;

    k_conv<<<dim3(B_), dim3(256), 0, stream>>>(
        emb_e, emb_rel,
        bnr_g, bnr_b, bnr_m, bnr_v,
        bn0_g, bn0_b, bn0_m, bn0_v,
        bn1_g, bn1_b, bn1_m, bn1_v,
        e1, rel, x1);

    k_fc<<<dim3(16, 16), dim3(256), 0, stream>>>(x1, fc_w, partials);

    k_reduce<<<dim3(100), dim3(256), 0, stream>>>(
        partials, fc_b, bn2_g, bn2_b, bn2_m, bn2_v, hT);

    k_scores<<<dim3((NE_ + 127) / 128, 8), dim3(256), 0, stream>>>(
        emb_e, bias, hT, (float*)d_out);
}

// Round 4
// 223.464 us; speedup vs baseline: 2.1590x; 1.6745x over previous
//
#include <hip/hip_runtime.h>
#include <hip/hip_bf16.h>
#include <hip/hip_fp16.h>

#define EPS 1e-5f
#define NE_ 100000
#define B_  256

typedef _Float16 half8 __attribute__((ext_vector_type(8)));
typedef float floatx16 __attribute__((ext_vector_type(16)));

// ws layout (fp32 element offsets):
//   x1       : [256][3600]          @ 0
//   partials : [16][256][100]       @ 921600
//   h16      : fp16 [14][256][8]    @ 1331200  (MFMA-A chunk-major, 57 KB)
#define WS_X1    0
#define WS_PART  921600
#define WS_H16   1331200

// =====================================================================
// Kernel 1: conv features. One block per sample.
// =====================================================================
__global__ __launch_bounds__(256) void k_conv(
    const float* __restrict__ emb_e,
    const float* __restrict__ emb_rel,
    const float* __restrict__ bnr_g, const float* __restrict__ bnr_b,
    const float* __restrict__ bnr_m, const float* __restrict__ bnr_v,
    const float* __restrict__ bn0_g, const float* __restrict__ bn0_b,
    const float* __restrict__ bn0_m, const float* __restrict__ bn0_v,
    const float* __restrict__ bn1_g, const float* __restrict__ bn1_b,
    const float* __restrict__ bn1_m, const float* __restrict__ bn1_v,
    const int* __restrict__ e1, const int* __restrict__ rel,
    float* __restrict__ x1)     // [256][3600]
{
    __shared__ float x0s[100];
    __shared__ float fs[2500];

    const int b = blockIdx.x;
    const int t = threadIdx.x;
    const int ei = e1[b];
    const int ri = rel[b];

    if (t < 100) {
        float sc = bn0_g[0] * rsqrtf(bn0_v[0] + EPS);
        float sh = bn0_b[0] - bn0_m[0] * sc;
        x0s[t] = emb_e[(size_t)ei * 100 + t] * sc + sh;
    }
    for (int j = t; j < 2500; j += 256) {
        float sc = bnr_g[j] * rsqrtf(bnr_v[j] + EPS);
        fs[j] = (emb_rel[(size_t)ri * 2500 + j] - bnr_m[j]) * sc + bnr_b[j];
    }
    __syncthreads();

    for (int idx = t; idx < 3600; idx += 256) {
        int c = idx / 36;
        int p = idx - c * 36;
        int hh = p / 6, ww = p - hh * 6;
        float sum = 0.f;
        #pragma unroll
        for (int ky = 0; ky < 5; ky++) {
            #pragma unroll
            for (int kx = 0; kx < 5; kx++) {
                sum += x0s[(hh + ky) * 10 + ww + kx] * fs[c * 25 + ky * 5 + kx];
            }
        }
        float sc = bn1_g[c] * rsqrtf(bn1_v[c] + EPS);
        float y = (sum - bn1_m[c]) * sc + bn1_b[c];
        x1[(size_t)b * 3600 + idx] = fmaxf(y, 0.f);
    }
}

// =====================================================================
// Kernel 2: fc GEMM, split-K (fp32). partials[ks][b][o].
// =====================================================================
__global__ __launch_bounds__(256) void k_fc(
    const float* __restrict__ x1,     // [256][3600]
    const float* __restrict__ fc_w,   // [3600][100]
    float* __restrict__ partials)     // [16][256][100]
{
    __shared__ float x1s[16][226];
    const int b0  = blockIdx.x * 16;
    const int ks  = blockIdx.y;
    const int kc0 = ks * 225;
    const int t = threadIdx.x;

    for (int idx = t; idx < 16 * 225; idx += 256) {
        int m = idx / 225, kk = idx - m * 225;
        x1s[m][kk] = x1[(size_t)(b0 + m) * 3600 + kc0 + kk];
    }
    __syncthreads();

    const int o  = t & 127;
    const int mg = t >> 7;
    if (o >= 100) return;

    float acc[8] = {0.f, 0.f, 0.f, 0.f, 0.f, 0.f, 0.f, 0.f};
    const float* wp = fc_w + (size_t)kc0 * 100 + o;

    for (int k0 = 0; k0 < 225; k0 += 9) {
        float wv[9];
        #pragma unroll
        for (int u = 0; u < 9; u++) wv[u] = wp[(size_t)(k0 + u) * 100];
        #pragma unroll
        for (int u = 0; u < 9; u++) {
            #pragma unroll
            for (int j = 0; j < 8; j++)
                acc[j] += x1s[mg + 2 * j][k0 + u] * wv[u];
        }
    }
    #pragma unroll
    for (int j = 0; j < 8; j++)
        partials[(size_t)ks * 25600 + (size_t)(b0 + mg + 2 * j) * 100 + o] = acc[j];
}

// =====================================================================
// Kernel 3: reduce split-K + fc_b + BN2 + ReLU -> h16 in MFMA-A layout
//   h16[(k>>3)*256*8 + b*8 + (k&7)] = fp16(h[b][k]), k in [0,100); pad [100,112)=0
// =====================================================================
__global__ __launch_bounds__(256) void k_reduce(
    const float* __restrict__ partials,   // [16][256][100]
    const float* __restrict__ fc_b,
    const float* __restrict__ bn2_g, const float* __restrict__ bn2_b,
    const float* __restrict__ bn2_m, const float* __restrict__ bn2_v,
    _Float16* __restrict__ h16)           // [14][256][8]
{
    const int flat = blockIdx.x * 256 + threadIdx.x;   // b*100 + o
    const int b = flat / 100;
    const int o = flat - b * 100;
    float s = fc_b[o];
    #pragma unroll
    for (int ks = 0; ks < 16; ks++) s += partials[(size_t)ks * 25600 + flat];
    float sc = bn2_g[o] * rsqrtf(bn2_v[o] + EPS);
    float y = (s - bn2_m[o]) * sc + bn2_b[o];
    y = fmaxf(y, 0.f);
    h16[((o >> 3) * 256 + b) * 8 + (o & 7)] = (_Float16)y;
    if (o < 12) {   // zero-pad k = 100..111
        int kp = 100 + o;
        h16[((kp >> 3) * 256 + b) * 8 + (kp & 7)] = (_Float16)0.f;
    }
}

// =====================================================================
// Kernel 4: out[b][e] = sigmoid(h[b].emb_e[e] + bias[e]) via f16 MFMA.
// No LDS. Wave = 128 m x 32 n strip. Block 256 = 4 waves (4 n-strips).
// grid = (ceil(NE/128), 2 m-halves).
// A-frag: half8 from h16 chunk-major (coalesced 16B/lane).
// B-frag: built from fp32 emb row, 2 x float4 + RNE cvt; pad k>=100 -> 0.
// D layout (32x32): col = lane&31, row = (r&3) + 8*(r>>2) + 4*(lane>>5).
// =====================================================================
__global__ __launch_bounds__(256) void k_scores(
    const float* __restrict__ emb_e,
    const float* __restrict__ bias,
    const _Float16* __restrict__ h16,   // [14][256][8]
    float* __restrict__ out)            // [256][NE]
{
    const int t    = threadIdx.x;
    const int wave = t >> 6;
    const int lane = t & 63;
    const int l31  = lane & 31;
    const int hf   = lane >> 5;

    const int n0     = blockIdx.x * 128 + wave * 32;
    const int m_base = blockIdx.y * 128;

    const int e  = n0 + l31;
    const int el = (e < NE_) ? e : (NE_ - 1);
    const float* erow = emb_e + (size_t)el * 100;

    // ---- B-frags for 7 k-chunks: k = kc*16 + hf*8 + j ----
    half8 bf[7];
    #pragma unroll
    for (int kc = 0; kc < 7; kc++) {
        const int k0 = kc * 16 + hf * 8;
        half8 h;
        if (k0 + 8 <= 100) {
            const float4 f0 = *(const float4*)(erow + k0);
            const float4 f1 = *(const float4*)(erow + k0 + 4);
            h[0] = (_Float16)f0.x; h[1] = (_Float16)f0.y;
            h[2] = (_Float16)f0.z; h[3] = (_Float16)f0.w;
            h[4] = (_Float16)f1.x; h[5] = (_Float16)f1.y;
            h[6] = (_Float16)f1.z; h[7] = (_Float16)f1.w;
        } else if (k0 < 100) {   // k0 == 96: 4 valid + 4 pad
            const float4 f0 = *(const float4*)(erow + k0);
            h[0] = (_Float16)f0.x; h[1] = (_Float16)f0.y;
            h[2] = (_Float16)f0.z; h[3] = (_Float16)f0.w;
            h[4] = (_Float16)0.f; h[5] = (_Float16)0.f;
            h[6] = (_Float16)0.f; h[7] = (_Float16)0.f;
        } else {                 // k0 >= 100: all pad
            #pragma unroll
            for (int j = 0; j < 8; j++) h[j] = (_Float16)0.f;
        }
        bf[kc] = h;
    }

    const half8* hA = (const half8*)h16;   // index = chunk8*256 + m

    floatx16 acc[4];
    #pragma unroll
    for (int mt = 0; mt < 4; mt++)
        #pragma unroll
        for (int r = 0; r < 16; r++) acc[mt][r] = 0.f;

    #pragma unroll
    for (int mt = 0; mt < 4; mt++) {
        const int m = m_base + mt * 32 + l31;
        #pragma unroll
        for (int kc = 0; kc < 7; kc++) {
            const half8 a = hA[(kc * 2 + hf) * 256 + m];
            acc[mt] = __builtin_amdgcn_mfma_f32_32x32x16_f16(a, bf[kc], acc[mt], 0, 0, 0);
        }
    }

    if (e < NE_) {
        const float bb = bias[e];
        #pragma unroll
        for (int mt = 0; mt < 4; mt++) {
            #pragma unroll
            for (int r = 0; r < 16; r++) {
                const int row = m_base + mt * 32 + (r & 3) + 8 * (r >> 2) + 4 * hf;
                const float v = 1.f / (1.f + __expf(-(acc[mt][r] + bb)));
                out[(size_t)row * NE_ + e] = v;
            }
        }
    }
}

extern "C" void kernel_launch(void* const* d_in, const int* in_sizes, int n_in,
                              void* d_out, int out_size, void* d_ws, size_t ws_size,
                              hipStream_t stream) {
    const float* emb_e   = (const float*)d_in[0];
    const float* emb_rel = (const float*)d_in[1];
    const float* bnr_g   = (const float*)d_in[2];
    const float* bnr_b   = (const float*)d_in[3];
    const float* bnr_m   = (const float*)d_in[4];
    const float* bnr_v   = (const float*)d_in[5];
    const float* bn0_g   = (const float*)d_in[6];
    const float* bn0_b   = (const float*)d_in[7];
    const float* bn0_m   = (const float*)d_in[8];
    const float* bn0_v   = (const float*)d_in[9];
    const float* bn1_g   = (const float*)d_in[10];
    const float* bn1_b   = (const float*)d_in[11];
    const float* bn1_m   = (const float*)d_in[12];
    const float* bn1_v   = (const float*)d_in[13];
    const float* fc_w    = (const float*)d_in[14];
    const float* fc_b    = (const float*)d_in[15];
    const float* bn2_g   = (const float*)d_in[16];
    const float* bn2_b   = (const float*)d_in[17];
    const float* bn2_m   = (const float*)d_in[18];
    const float* bn2_v   = (const float*)d_in[19];
    const float* bias    = (const float*)d_in[20];
    const int* e1  = (const int*)d_in[21];
    const int* rel = (const int*)d_in[22];

    float* ws       = (float*)d_ws;
    float* x1       = ws + WS_X1;
    float* partials = ws + WS_PART;
    _Float16* h16   = (_Float16*)(ws + WS_H16);

    k_conv<<<dim3(B_), dim3(256), 0, stream>>>(
        emb_e, emb_rel,
        bnr_g, bnr_b, bnr_m, bnr_v,
        bn0_g, bn0_b, bn0_m, bn0_v,
        bn1_g, bn1_b, bn1_m, bn1_v,
        e1, rel, x1);

    k_fc<<<dim3(16, 16), dim3(256), 0, stream>>>(x1, fc_w, partials);

    k_reduce<<<dim3(100), dim3(256), 0, stream>>>(
        partials, fc_b, bn2_g, bn2_b, bn2_m, bn2_v, h16);

    k_scores<<<dim3((NE_ + 127) / 128, 2), dim3(256), 0, stream>>>(
        emb_e, bias, h16, (float*)d_out);
}